// Round 3
// baseline (318.523 us; speedup 1.0000x reference)
//
#include <hip/hip_runtime.h>
#include <hip/hip_bf16.h>

// Problem dims (fixed by reference setup_inputs)
#define B_  4
#define L_  4096
#define H_  1024
#define N_  64
#define LN_EPS 1e-5f
#define CH  32           // scan chunk length (steps per LDS reduce)
#define NC  (L_ / CH)

typedef float v2f __attribute__((ext_vector_type(2)));
typedef float v4f __attribute__((ext_vector_type(4)));

// ---------------------------------------------------------------------------
// k_prep: Lambda = -exp(LR) + i*exp(LI); a = exp(Lambda);
//         C = (CR + i*CI) * (exp(Lambda)-1)/Lambda   -> Crr/Cii [H][N]
// ---------------------------------------------------------------------------
__global__ __launch_bounds__(256) void k_prep(
    const float* __restrict__ LR, const float* __restrict__ LI,
    const float* __restrict__ CR, const float* __restrict__ CI,
    float* __restrict__ Are, float* __restrict__ Aim,
    float* __restrict__ Crr, float* __restrict__ Cii)
{
    int idx = blockIdx.x * 256 + threadIdx.x;   // 0 .. H*N-1
    int n = idx & (N_ - 1);
    float lr = -expf(LR[n]);      // Re(Lambda) < 0
    float li =  expf(LI[n]);      // Im(Lambda)
    float er = expf(lr);
    float Er = er * cosf(li);
    float Ei = er * sinf(li);
    // w = (E-1)/Lambda
    float nr = Er - 1.0f, ni = Ei;
    float m2 = lr * lr + li * li;
    float inv = 1.0f / m2;
    float wr = (nr * lr + ni * li) * inv;
    float wi = (ni * lr - nr * li) * inv;
    float cr = CR[idx], ci = CI[idx];
    Crr[idx] = cr * wr - ci * wi;
    Cii[idx] = cr * wi + ci * wr;
    if (idx < N_) { Are[idx] = Er; Aim[idx] = Ei; }
}

// ---------------------------------------------------------------------------
// k_stats: per (b,l) row of H=1024: mean and rstd
// ---------------------------------------------------------------------------
__global__ __launch_bounds__(256) void k_stats(
    const float* __restrict__ x, float2* __restrict__ stats)
{
    int row = blockIdx.x;                      // b*L + l
    const float4* xr = (const float4*)(x + (size_t)row * H_);
    float4 v = xr[threadIdx.x];
    float s1 = v.x + v.y + v.z + v.w;
    float s2 = v.x * v.x + v.y * v.y + v.z * v.z + v.w * v.w;
    for (int off = 32; off; off >>= 1) {
        s1 += __shfl_down(s1, off, 64);
        s2 += __shfl_down(s2, off, 64);
    }
    __shared__ float a1[4], a2[4];
    int w = threadIdx.x >> 6, lane = threadIdx.x & 63;
    if (lane == 0) { a1[w] = s1; a2[w] = s2; }
    __syncthreads();
    if (threadIdx.x == 0) {
        float t1 = a1[0] + a1[1] + a1[2] + a1[3];
        float t2 = a2[0] + a2[1] + a2[2] + a2[3];
        float mu  = t1 * (1.0f / H_);
        float var = t2 * (1.0f / H_) - mu * mu;
        stats[row] = make_float2(mu, rsqrtf(var + LN_EPS));
    }
}

// ---------------------------------------------------------------------------
// k_norm_t: xn_t[b,h,l] = LN(x[b,l,h]) via 64x64 LDS tile transpose
// grid: (H/64, L/64, B), block 256
// ---------------------------------------------------------------------------
__global__ __launch_bounds__(256) void k_norm_t(
    const float* __restrict__ x, const float2* __restrict__ stats,
    const float* __restrict__ gamma, const float* __restrict__ beta,
    float* __restrict__ xt)
{
    __shared__ float tile[64][65];
    int h0 = blockIdx.x * 64, l0 = blockIdx.y * 64, b = blockIdx.z;
    int tx = threadIdx.x & 63;
    int ty = threadIdx.x >> 6;
    float g  = gamma[h0 + tx];
    float be = beta[h0 + tx];
    #pragma unroll
    for (int r = 0; r < 16; ++r) {
        int ly = r * 4 + ty;
        float2 st = stats[b * L_ + l0 + ly];
        float v = x[((size_t)b * L_ + (l0 + ly)) * H_ + h0 + tx];
        tile[ly][tx] = (v - st.x) * st.y * g + be;
    }
    __syncthreads();
    #pragma unroll
    for (int r = 0; r < 16; ++r) {
        int hy = r * 4 + ty;
        xt[((size_t)(b * H_ + h0 + hy)) * L_ + l0 + tx] = tile[tx][hy];
    }
}

// ---------------------------------------------------------------------------
// k_scan: one WAVE per (b,h) row; lane = mode n.  xt -> yt.
// Fused state z = C*s:  z' = a*z + C*u ;  y = sum_n Re(z_n) + D*u
// Packed fp32 (VOP3P): 3 instrs per step via op_sel broadcast + swap/neg.
// d-values written to LDS in pairs (ds_write_b64), transpose-reduced.
// grid: B*H blocks of 64.
// ---------------------------------------------------------------------------
__global__ __launch_bounds__(64) void k_scan(
    const float* __restrict__ xt, float* __restrict__ yt,
    const float* __restrict__ Are, const float* __restrict__ Aim,
    const float* __restrict__ Crr, const float* __restrict__ Cii,
    const float* __restrict__ D)
{
    __shared__ v2f rd2[16][65];       // [step-pair][mode] (+1 pad)
    const int lane = threadIdx.x;
    const int gw = blockIdx.x;            // b*H + h
    const int h = gw & (H_ - 1);

    const float are = Are[lane], aim = Aim[lane];
    v2f a2   = {are, are};
    v2f ai2  = {aim, aim};
    v2f C2   = {Crr[h * N_ + lane], Cii[h * N_ + lane]};
    const float Dh = D[h];

    const float* urow  = xt + (size_t)gw * L_;
    const v4f*   urow4 = (const v4f*)urow;
    float* orow = yt + (size_t)gw * L_;

    v2f z = {0.0f, 0.0f};

    const int r = lane & 31, hf = lane >> 5;
    // reduce base: step r -> row r>>1, component r&1, mode-half hf
    const float* rp = (const float*)rd2 + (r >> 1) * 130 + hf * 64 + (r & 1);

    // One step-pair: u_even = uq.lo-half sel, u_odd = uq.hi-half sel.
    //  cu = (Cr*u, Ci*u); t = a*z + cu; z = (-aim*z.hi + t.lo, aim*z.lo + t.hi)
#define STEP_PAIR(uq, dp) do {                                               \
    v2f cu_, t_;                                                             \
    asm("v_pk_mul_f32 %0, %1, %2 op_sel:[0,0] op_sel_hi:[1,0]"               \
        : "=v"(cu_) : "v"(C2), "v"(uq));                                     \
    asm("v_pk_fma_f32 %0, %1, %2, %3"                                        \
        : "=v"(t_) : "v"(a2), "v"(z), "v"(cu_));                             \
    asm("v_pk_fma_f32 %0, %1, %0, %2 op_sel:[0,1,0] op_sel_hi:[1,0,1] neg_lo:[0,1,0]" \
        : "+v"(z) : "v"(ai2), "v"(t_));                                      \
    dp.x = z.x;                                                              \
    asm("v_pk_mul_f32 %0, %1, %2 op_sel:[0,1] op_sel_hi:[1,1]"               \
        : "=v"(cu_) : "v"(C2), "v"(uq));                                     \
    asm("v_pk_fma_f32 %0, %1, %2, %3"                                        \
        : "=v"(t_) : "v"(a2), "v"(z), "v"(cu_));                             \
    asm("v_pk_fma_f32 %0, %1, %0, %2 op_sel:[0,1,0] op_sel_hi:[1,0,1] neg_lo:[0,1,0]" \
        : "+v"(z) : "v"(ai2), "v"(t_));                                      \
    dp.y = z.x;                                                              \
} while (0)

#define DO_CHUNK(V, uo, c) do {                                              \
    _Pragma("unroll")                                                        \
    for (int q = 0; q < 16; ++q) {                                           \
        v2f uq_ = (q & 1) ? (V)[q >> 1].hi : (V)[q >> 1].lo;                 \
        v2f dp_; STEP_PAIR(uq_, dp_);                                        \
        rd2[q][lane] = dp_;                                                  \
    }                                                                        \
    __syncthreads();                                                         \
    float p0 = 0.f, p1 = 0.f, p2 = 0.f, p3 = 0.f;                            \
    _Pragma("unroll")                                                        \
    for (int j = 0; j < 32; j += 4) {                                        \
        p0 += rp[2 * j];       p1 += rp[2 * (j + 1)];                        \
        p2 += rp[2 * (j + 2)]; p3 += rp[2 * (j + 3)];                        \
    }                                                                        \
    float acc_ = (p0 + p1) + (p2 + p3);                                      \
    acc_ += __shfl_xor(acc_, 32, 64);                                        \
    if (lane < 32) orow[(c) * CH + lane] = fmaf(Dh, (uo), acc_);             \
    __syncthreads();                                                         \
} while (0)

    v4f VA[8], VB[8];
    float uoA, uoB;
    #pragma unroll
    for (int k = 0; k < 8; ++k) VA[k] = urow4[k];
    uoA = urow[lane & 31];

    #pragma unroll 1
    for (int c = 0; c < NC; c += 2) {
        // prefetch chunk c+1 (always exists; NC even)
        #pragma unroll
        for (int k = 0; k < 8; ++k) VB[k] = urow4[(c + 1) * 8 + k];
        uoB = urow[(c + 1) * CH + (lane & 31)];
        DO_CHUNK(VA, uoA, c);
        if (c + 2 < NC) {
            #pragma unroll
            for (int k = 0; k < 8; ++k) VA[k] = urow4[(c + 2) * 8 + k];
            uoA = urow[(c + 2) * CH + (lane & 31)];
        }
        DO_CHUNK(VB, uoB, c + 1);
    }
#undef STEP_PAIR
#undef DO_CHUNK
}

// ---------------------------------------------------------------------------
// k_out: out[b,l,h] = y_t[b,h,l]  (64x64 LDS tile transpose)
// grid: (H/64, L/64, B), block 256
// ---------------------------------------------------------------------------
__global__ __launch_bounds__(256) void k_out(
    const float* __restrict__ yt, float* __restrict__ out)
{
    __shared__ float tile[64][65];
    int h0 = blockIdx.x * 64, l0 = blockIdx.y * 64, b = blockIdx.z;
    int tx = threadIdx.x & 63;
    int ty = threadIdx.x >> 6;
    #pragma unroll
    for (int r = 0; r < 16; ++r) {
        int hy = r * 4 + ty;
        tile[hy][tx] = yt[((size_t)(b * H_ + h0 + hy)) * L_ + l0 + tx];
    }
    __syncthreads();
    #pragma unroll
    for (int r = 0; r < 16; ++r) {
        int ly = r * 4 + ty;
        out[((size_t)b * L_ + (l0 + ly)) * H_ + h0 + tx] = tile[tx][ly];
    }
}

// ---------------------------------------------------------------------------
extern "C" void kernel_launch(void* const* d_in, const int* in_sizes, int n_in,
                              void* d_out, int out_size, void* d_ws, size_t ws_size,
                              hipStream_t stream)
{
    const float* x     = (const float*)d_in[0];
    const float* gamma = (const float*)d_in[1];
    const float* beta  = (const float*)d_in[2];
    const float* LR    = (const float*)d_in[3];
    const float* LI    = (const float*)d_in[4];
    const float* CR    = (const float*)d_in[5];
    const float* CI    = (const float*)d_in[6];
    const float* D     = (const float*)d_in[7];
    float* out = (float*)d_out;

    const size_t BHL  = (size_t)B_ * H_ * L_;
    const size_t tailElems = 2 * (size_t)B_ * L_ + 2 * N_ + 2 * (size_t)H_ * N_;
    const bool big = ws_size >= (2 * BHL + tailElems) * sizeof(float);

    // workspace layout: xt [, yt], stats, Are, Aim, Crr, Cii
    float* xt = (float*)d_ws;                         // B*H*L floats
    float* yt = big ? xt + BHL : xt;                  // out-of-place if room
    float* tail = big ? yt + BHL : xt + BHL;
    float2* st  = (float2*)tail;                      // B*L float2
    float*  Are = (float*)(st + (size_t)B_ * L_);     // N
    float*  Aim = Are + N_;
    float*  Crr = Aim + N_;                           // H*N
    float*  Cii = Crr + (size_t)H_ * N_;

    k_prep <<<dim3((H_ * N_) / 256), dim3(256), 0, stream>>>(LR, LI, CR, CI, Are, Aim, Crr, Cii);
    k_stats<<<dim3(B_ * L_),         dim3(256), 0, stream>>>(x, st);
    k_norm_t<<<dim3(H_/64, L_/64, B_), dim3(256), 0, stream>>>(x, st, gamma, beta, xt);
    k_scan <<<dim3(B_ * H_),         dim3(64),  0, stream>>>(xt, yt, Are, Aim, Crr, Cii, D);
    k_out  <<<dim3(H_/64, L_/64, B_), dim3(256), 0, stream>>>(yt, out);
}

// Round 4
// 274.499 us; speedup vs baseline: 1.1604x; 1.1604x over previous
//
#include <hip/hip_runtime.h>
#include <hip/hip_bf16.h>

// Problem dims (fixed by reference setup_inputs)
#define B_  4
#define L_  4096
#define H_  1024
#define N_  64
#define LN_EPS 1e-5f
#define CH  32           // scan chunk length (steps per LDS reduce)
#define NC  (L_ / CH)
#define RSTR 68          // LDS row stride (floats): 16B-aligned, <=2-way banks

typedef float v4f __attribute__((ext_vector_type(4)));

// ---------------------------------------------------------------------------
// k_prep: Lambda = -exp(LR) + i*exp(LI); a = exp(Lambda);
//         C = (CR + i*CI) * (exp(Lambda)-1)/Lambda   -> Crr/Cii [H][N]
// ---------------------------------------------------------------------------
__global__ __launch_bounds__(256) void k_prep(
    const float* __restrict__ LR, const float* __restrict__ LI,
    const float* __restrict__ CR, const float* __restrict__ CI,
    float* __restrict__ Are, float* __restrict__ Aim,
    float* __restrict__ Crr, float* __restrict__ Cii)
{
    int idx = blockIdx.x * 256 + threadIdx.x;   // 0 .. H*N-1
    int n = idx & (N_ - 1);
    float lr = -expf(LR[n]);      // Re(Lambda) < 0
    float li =  expf(LI[n]);      // Im(Lambda)
    float er = expf(lr);
    float Er = er * cosf(li);
    float Ei = er * sinf(li);
    // w = (E-1)/Lambda
    float nr = Er - 1.0f, ni = Ei;
    float m2 = lr * lr + li * li;
    float inv = 1.0f / m2;
    float wr = (nr * lr + ni * li) * inv;
    float wi = (ni * lr - nr * li) * inv;
    float cr = CR[idx], ci = CI[idx];
    Crr[idx] = cr * wr - ci * wi;
    Cii[idx] = cr * wi + ci * wr;
    if (idx < N_) { Are[idx] = Er; Aim[idx] = Ei; }
}

// ---------------------------------------------------------------------------
// k_stats: per (b,l) row of H=1024: mean and rstd
// ---------------------------------------------------------------------------
__global__ __launch_bounds__(256) void k_stats(
    const float* __restrict__ x, float2* __restrict__ stats)
{
    int row = blockIdx.x;                      // b*L + l
    const float4* xr = (const float4*)(x + (size_t)row * H_);
    float4 v = xr[threadIdx.x];
    float s1 = v.x + v.y + v.z + v.w;
    float s2 = v.x * v.x + v.y * v.y + v.z * v.z + v.w * v.w;
    for (int off = 32; off; off >>= 1) {
        s1 += __shfl_down(s1, off, 64);
        s2 += __shfl_down(s2, off, 64);
    }
    __shared__ float a1[4], a2[4];
    int w = threadIdx.x >> 6, lane = threadIdx.x & 63;
    if (lane == 0) { a1[w] = s1; a2[w] = s2; }
    __syncthreads();
    if (threadIdx.x == 0) {
        float t1 = a1[0] + a1[1] + a1[2] + a1[3];
        float t2 = a2[0] + a2[1] + a2[2] + a2[3];
        float mu  = t1 * (1.0f / H_);
        float var = t2 * (1.0f / H_) - mu * mu;
        stats[row] = make_float2(mu, rsqrtf(var + LN_EPS));
    }
}

// ---------------------------------------------------------------------------
// k_norm_t: xn_t[b,h,l] = LN(x[b,l,h]) via 64x64 LDS tile transpose
// grid: (H/64, L/64, B), block 256
// ---------------------------------------------------------------------------
__global__ __launch_bounds__(256) void k_norm_t(
    const float* __restrict__ x, const float2* __restrict__ stats,
    const float* __restrict__ gamma, const float* __restrict__ beta,
    float* __restrict__ xt)
{
    __shared__ float tile[64][65];
    int h0 = blockIdx.x * 64, l0 = blockIdx.y * 64, b = blockIdx.z;
    int tx = threadIdx.x & 63;
    int ty = threadIdx.x >> 6;
    float g  = gamma[h0 + tx];
    float be = beta[h0 + tx];
    #pragma unroll
    for (int r = 0; r < 16; ++r) {
        int ly = r * 4 + ty;
        float2 st = stats[b * L_ + l0 + ly];
        float v = x[((size_t)b * L_ + (l0 + ly)) * H_ + h0 + tx];
        tile[ly][tx] = (v - st.x) * st.y * g + be;
    }
    __syncthreads();
    #pragma unroll
    for (int r = 0; r < 16; ++r) {
        int hy = r * 4 + ty;
        xt[((size_t)(b * H_ + h0 + hy)) * L_ + l0 + tx] = tile[tx][hy];
    }
}

// ---------------------------------------------------------------------------
// k_scan: one WAVE per (b,h) row; lane = mode n.  xt -> yt.
//   s' = a*s + u ;  d = Cr*Re(s') - Ci*Im(s') ;  y = sum_n d_n + D*u
// Scalar FMAs (packed fp32 has no issue-rate advantage on CDNA4).
// Ping-pong chunk registers (no copy), b128 reduce reads, stride-68 LDS.
// grid: B*H blocks of 64.
// ---------------------------------------------------------------------------
__global__ __launch_bounds__(64) void k_scan(
    const float* __restrict__ xt, float* __restrict__ yt,
    const float* __restrict__ Are, const float* __restrict__ Aim,
    const float* __restrict__ Crr, const float* __restrict__ Cii,
    const float* __restrict__ D)
{
    __shared__ float rd[CH][RSTR];        // 32 x 68 floats = 8704 B
    const int lane = threadIdx.x;
    const int gw = blockIdx.x;            // b*H + h
    const int h = gw & (H_ - 1);

    const float ar  = Are[lane], ai = Aim[lane];
    const float Cr  = Crr[h * N_ + lane];
    const float nCi = -Cii[h * N_ + lane];
    const float Dh  = D[h];

    const float* __restrict__ urow  = xt + (size_t)gw * L_;
    const v4f*   __restrict__ urow4 = (const v4f*)urow;
    float* __restrict__ orow = yt + (size_t)gw * L_;

    float zr = 0.0f, zi = 0.0f;
    const int r = lane & 31, hf = lane >> 5;
    const v4f* rbase = (const v4f*)&rd[r][hf * 32];   // 16B aligned

#define DO_CHUNK(U4, uo, c) do {                                             \
    _Pragma("unroll")                                                        \
    for (int i = 0; i < CH; ++i) {                                           \
        const int q_ = i >> 2, m_ = i & 3;                                   \
        float ui = (m_ == 0) ? (U4)[q_].x : (m_ == 1) ? (U4)[q_].y           \
                 : (m_ == 2) ? (U4)[q_].z : (U4)[q_].w;                      \
        float t_  = fmaf(ar, zr, ui);                                        \
        float nr_ = fmaf(-ai, zi, t_);                                       \
        float ni_ = fmaf(ar, zi, ai * zr);                                   \
        zr = nr_; zi = ni_;                                                  \
        rd[i][lane] = fmaf(nCi, ni_, Cr * nr_);                              \
    }                                                                        \
    __syncthreads();                                                         \
    {                                                                        \
        v4f q0 = rbase[0], q1 = rbase[1], q2 = rbase[2], q3 = rbase[3];      \
        q0 += rbase[4]; q1 += rbase[5]; q2 += rbase[6]; q3 += rbase[7];      \
        v4f qq = (q0 + q1) + (q2 + q3);                                      \
        float acc = (qq.x + qq.y) + (qq.z + qq.w);                           \
        acc += __shfl_xor(acc, 32, 64);                                      \
        if (lane < 32) orow[(c) * CH + lane] = fmaf(Dh, (uo), acc);          \
    }                                                                        \
    __syncthreads();                                                         \
} while (0)

    v4f A4[8], B4[8];
    float uoA, uoB;
    #pragma unroll
    for (int k = 0; k < 8; ++k) A4[k] = urow4[k];
    uoA = urow[lane & 31];

    #pragma unroll 1
    for (int c = 0; c < NC; c += 2) {
        // prefetch chunk c+1 (always exists; NC even)
        #pragma unroll
        for (int k = 0; k < 8; ++k) B4[k] = urow4[(c + 1) * 8 + k];
        uoB = urow[(c + 1) * CH + (lane & 31)];
        DO_CHUNK(A4, uoA, c);
        if (c + 2 < NC) {
            #pragma unroll
            for (int k = 0; k < 8; ++k) A4[k] = urow4[(c + 2) * 8 + k];
            uoA = urow[(c + 2) * CH + (lane & 31)];
        }
        DO_CHUNK(B4, uoB, c + 1);
    }
#undef DO_CHUNK
}

// ---------------------------------------------------------------------------
// k_out: out[b,l,h] = y_t[b,h,l]  (64x64 LDS tile transpose)
// grid: (H/64, L/64, B), block 256
// ---------------------------------------------------------------------------
__global__ __launch_bounds__(256) void k_out(
    const float* __restrict__ yt, float* __restrict__ out)
{
    __shared__ float tile[64][65];
    int h0 = blockIdx.x * 64, l0 = blockIdx.y * 64, b = blockIdx.z;
    int tx = threadIdx.x & 63;
    int ty = threadIdx.x >> 6;
    #pragma unroll
    for (int r = 0; r < 16; ++r) {
        int hy = r * 4 + ty;
        tile[hy][tx] = yt[((size_t)(b * H_ + h0 + hy)) * L_ + l0 + tx];
    }
    __syncthreads();
    #pragma unroll
    for (int r = 0; r < 16; ++r) {
        int ly = r * 4 + ty;
        out[((size_t)b * L_ + (l0 + ly)) * H_ + h0 + tx] = tile[tx][ly];
    }
}

// ---------------------------------------------------------------------------
extern "C" void kernel_launch(void* const* d_in, const int* in_sizes, int n_in,
                              void* d_out, int out_size, void* d_ws, size_t ws_size,
                              hipStream_t stream)
{
    const float* x     = (const float*)d_in[0];
    const float* gamma = (const float*)d_in[1];
    const float* beta  = (const float*)d_in[2];
    const float* LR    = (const float*)d_in[3];
    const float* LI    = (const float*)d_in[4];
    const float* CR    = (const float*)d_in[5];
    const float* CI    = (const float*)d_in[6];
    const float* D     = (const float*)d_in[7];
    float* out = (float*)d_out;

    const size_t BHL  = (size_t)B_ * H_ * L_;
    const size_t tailElems = 2 * (size_t)B_ * L_ + 2 * N_ + 2 * (size_t)H_ * N_;
    const bool big = ws_size >= (2 * BHL + tailElems) * sizeof(float);

    // workspace layout: xt [, yt], stats, Are, Aim, Crr, Cii
    float* xt = (float*)d_ws;                         // B*H*L floats
    float* yt = big ? xt + BHL : xt;                  // out-of-place if room
    float* tail = big ? yt + BHL : xt + BHL;
    float2* st  = (float2*)tail;                      // B*L float2
    float*  Are = (float*)(st + (size_t)B_ * L_);     // N
    float*  Aim = Are + N_;
    float*  Crr = Aim + N_;                           // H*N
    float*  Cii = Crr + (size_t)H_ * N_;

    k_prep <<<dim3((H_ * N_) / 256), dim3(256), 0, stream>>>(LR, LI, CR, CI, Are, Aim, Crr, Cii);
    k_stats<<<dim3(B_ * L_),         dim3(256), 0, stream>>>(x, st);
    k_norm_t<<<dim3(H_/64, L_/64, B_), dim3(256), 0, stream>>>(x, st, gamma, beta, xt);
    k_scan <<<dim3(B_ * H_),         dim3(64),  0, stream>>>(xt, yt, Are, Aim, Crr, Cii, D);
    k_out  <<<dim3(H_/64, L_/64, B_), dim3(256), 0, stream>>>(yt, out);
}

// Round 5
// 126.645 us; speedup vs baseline: 2.5151x; 2.1675x over previous
//
#include <hip/hip_runtime.h>
#include <hip/hip_bf16.h>

// Problem dims (fixed by reference setup_inputs)
#define B_  4
#define L_  4096
#define H_  1024
#define N_  64
#define LN_EPS 1e-5f
#define T_  64            // chunk length
#define NCH (L_ / T_)     // 64 chunks per row

typedef __bf16 bf16x8 __attribute__((ext_vector_type(8)));
typedef __bf16 bf16x4 __attribute__((ext_vector_type(4)));
typedef float  f32x4  __attribute__((ext_vector_type(4)));

#define MFMA(a, b, c) __builtin_amdgcn_mfma_f32_16x16x32_bf16((a), (b), (c), 0, 0, 0)

// ---------------------------------------------------------------------------
// k_prep: C~ = (CR + i CI) * (exp(Lambda)-1)/Lambda  -> Crr/Cii [H][N]
// ---------------------------------------------------------------------------
__global__ __launch_bounds__(256) void k_prep(
    const float* __restrict__ LR, const float* __restrict__ LI,
    const float* __restrict__ CR, const float* __restrict__ CI,
    float* __restrict__ Crr, float* __restrict__ Cii)
{
    int idx = blockIdx.x * 256 + threadIdx.x;   // 0 .. H*N-1
    int n = idx & (N_ - 1);
    float lr = -expf(LR[n]);
    float li =  expf(LI[n]);
    float er = expf(lr);
    float Er = er * cosf(li);
    float Ei = er * sinf(li);
    float nr = Er - 1.0f, ni = Ei;
    float inv = 1.0f / (lr * lr + li * li);
    float wr = (nr * lr + ni * li) * inv;
    float wi = (ni * lr - nr * li) * inv;
    float cr = CR[idx], ci = CI[idx];
    Crr[idx] = cr * wr - ci * wi;
    Cii[idx] = cr * wi + ci * wr;
}

// ---------------------------------------------------------------------------
// k_tables: P[d][n] = a_n^d (d=0..64) fp32; Ag[n'][j] = Vandermonde a^(63-j)
// bf16 (rows 0-63 Re, 64-127 Im); a64 = a^64.
// grid: 65 blocks x 64
// ---------------------------------------------------------------------------
__global__ __launch_bounds__(64) void k_tables(
    const float* __restrict__ LR, const float* __restrict__ LI,
    float* __restrict__ PR, float* __restrict__ PI,
    float* __restrict__ AR64, float* __restrict__ AI64,
    __bf16* __restrict__ Ag)
{
    int d = blockIdx.x;        // 0..64
    int n = threadIdx.x;       // 0..63
    float lr = -expf(LR[n]);
    float li =  expf(LI[n]);
    float e  = expf((float)d * lr);
    float pr = e * cosf((float)d * li);
    float pi = e * sinf((float)d * li);
    PR[d * N_ + n] = pr;
    PI[d * N_ + n] = pi;
    if (d == 64) { AR64[n] = pr; AI64[n] = pi; }
    if (d <= 63) {
        Ag[n * 64 + (63 - d)]          = (__bf16)pr;
        Ag[(64 + n) * 64 + (63 - d)]   = (__bf16)pi;
    }
}

// ---------------------------------------------------------------------------
// k_stats: per (b,l) row of H=1024: mean and rstd
// ---------------------------------------------------------------------------
__global__ __launch_bounds__(256) void k_stats(
    const float* __restrict__ x, float2* __restrict__ stats)
{
    int row = blockIdx.x;
    const float4* xr = (const float4*)(x + (size_t)row * H_);
    float4 v = xr[threadIdx.x];
    float s1 = v.x + v.y + v.z + v.w;
    float s2 = v.x * v.x + v.y * v.y + v.z * v.z + v.w * v.w;
    for (int off = 32; off; off >>= 1) {
        s1 += __shfl_down(s1, off, 64);
        s2 += __shfl_down(s2, off, 64);
    }
    __shared__ float a1[4], a2[4];
    int w = threadIdx.x >> 6;
    if ((threadIdx.x & 63) == 0) { a1[w] = s1; a2[w] = s2; }
    __syncthreads();
    if (threadIdx.x == 0) {
        float t1 = a1[0] + a1[1] + a1[2] + a1[3];
        float t2 = a2[0] + a2[1] + a2[2] + a2[3];
        float mu  = t1 * (1.0f / H_);
        float var = t2 * (1.0f / H_) - mu * mu;
        stats[row] = make_float2(mu, rsqrtf(var + LN_EPS));
    }
}

// ---------------------------------------------------------------------------
// k_norm_t: xt[b,h,l] = LN(x[b,l,h]) via 64x64 LDS tile transpose
// ---------------------------------------------------------------------------
__global__ __launch_bounds__(256) void k_norm_t(
    const float* __restrict__ x, const float2* __restrict__ stats,
    const float* __restrict__ gamma, const float* __restrict__ beta,
    float* __restrict__ xt)
{
    __shared__ float tile[64][65];
    int h0 = blockIdx.x * 64, l0 = blockIdx.y * 64, b = blockIdx.z;
    int tx = threadIdx.x & 63;
    int ty = threadIdx.x >> 6;
    float g  = gamma[h0 + tx];
    float be = beta[h0 + tx];
    #pragma unroll
    for (int r = 0; r < 16; ++r) {
        int ly = r * 4 + ty;
        float2 st = stats[b * L_ + l0 + ly];
        float v = x[((size_t)b * L_ + (l0 + ly)) * H_ + h0 + tx];
        tile[ly][tx] = (v - st.x) * st.y * g + be;
    }
    __syncthreads();
    #pragma unroll
    for (int r = 0; r < 16; ++r) {
        int hy = r * 4 + ty;
        xt[((size_t)(b * H_ + h0 + hy)) * L_ + l0 + tx] = tile[tx][hy];
    }
}

// ---------------------------------------------------------------------------
// k_main: one block per h (1024 blocks x 512 threads = 8 waves).
// Phase 0: build W[t,n'] (=C~*a^(t+1)), K_h, TriK[t,j] in LDS; copy A table.
// Phase 1: load U (4 rows) -> bf16 LDS [c'][j];  V = A @ U (MFMA) -> VS.
// Phase 2: per-b chunk scan s[c]=a64*s+V[c] (fp32), S -> VS (bf16, Im negated)
// Phase 3: Y = W @ S + TriK @ U (MFMA), + D*u, store fp32 to yt rows.
// In-place safe: block reads exactly the rows it writes, all reads in phase 1.
// ---------------------------------------------------------------------------
__global__ __launch_bounds__(512) void k_main(
    const float* __restrict__ xt, float* __restrict__ yt,
    const float* __restrict__ Crr, const float* __restrict__ Cii,
    const float* __restrict__ PR, const float* __restrict__ PI,
    const float* __restrict__ AR64, const float* __restrict__ AI64,
    const __bf16* __restrict__ Ag, const float* __restrict__ Dv)
{
    __shared__ __attribute__((aligned(16))) __bf16 Alds[128][72];
    __shared__ __attribute__((aligned(16))) __bf16 Ulds[256][72];
    __shared__ __attribute__((aligned(16))) __bf16 VS[260][136];
    __shared__ __attribute__((aligned(16))) __bf16 Wlds[64][136];
    __shared__ __attribute__((aligned(16))) __bf16 Klds[64][72];
    __shared__ float Kh[64];

    const int h   = blockIdx.x;
    const int tid = threadIdx.x;           // 0..511
    const int wv  = tid >> 6;              // wave 0..7
    const int ln  = tid & 63;
    const int lr  = ln & 15;               // MFMA row/col lane
    const int kg  = ln >> 4;               // MFMA k-group 0..3

    const float Dh  = Dv[h];
    const float CRh = Crr[h * N_ + ln];    // this thread's mode = ln
    const float CIh = Cii[h * N_ + ln];
    const float aR  = AR64[ln], aI = AI64[ln];

    // ---- issue U global loads early (hide HBM latency under phase 0) ----
    float4 ur[8];
    #pragma unroll
    for (int s = 0; s < 8; ++s) {
        int q = tid + s * 512;                     // 0..4095
        int b = q >> 10, pos = (q & 1023) << 2;
        ur[s] = *(const float4*)&xt[((size_t)(b * H_ + h)) * L_ + pos];
    }

    // ---- A table: 4096 dwords global -> LDS ----
    const uint32_t* Ag32 = (const uint32_t*)Ag;
    #pragma unroll
    for (int i = 0; i < 8; ++i) {
        int d = tid + i * 512;
        int row = d >> 5, cd = d & 31;
        *(uint32_t*)&Alds[row][cd * 2] = Ag32[d];
    }

    // ---- W[t][n], W[t][64+n] = C~ * a^(t+1) ----
    #pragma unroll
    for (int s = 0; s < 8; ++s) {
        int t = (tid >> 6) + s * 8;
        float pr = PR[(t + 1) * N_ + ln], pi = PI[(t + 1) * N_ + ln];
        Wlds[t][ln]       = (__bf16)(CRh * pr - CIh * pi);
        Wlds[t][64 + ln]  = (__bf16)(CRh * pi + CIh * pr);
    }

    // ---- K_h[d] = sum_n Re(C~ a^d), wave wv handles d = 8wv..8wv+7 ----
    #pragma unroll
    for (int s = 0; s < 8; ++s) {
        int d = wv * 8 + s;
        float term = CRh * PR[d * N_ + ln] - CIh * PI[d * N_ + ln];
        for (int off = 32; off; off >>= 1) term += __shfl_xor(term, off, 64);
        if (ln == 0) Kh[d] = term;
    }
    __syncthreads();

    // ---- TriK[t][j] = (t>=j) ? K_h[t-j] : 0 ----
    #pragma unroll
    for (int s = 0; s < 8; ++s) {
        int idx = tid + s * 512;
        int t = idx >> 6, j = idx & 63;
        Klds[t][j] = (t >= j) ? (__bf16)Kh[t - j] : (__bf16)0.0f;
    }

    // ---- U regs -> bf16 LDS [c' = b*64+c][j] ----
    #pragma unroll
    for (int s = 0; s < 8; ++s) {
        int q = tid + s * 512;
        int b = q >> 10, pos = (q & 1023) << 2;
        int c = pos >> 6, j = pos & 63;
        bf16x4 pv = {(__bf16)ur[s].x, (__bf16)ur[s].y,
                     (__bf16)ur[s].z, (__bf16)ur[s].w};
        *(bf16x4*)&Ulds[b * 64 + c][j] = pv;
    }
    __syncthreads();

    // ---- Phase 1 MFMA: V[n'=wv tile][c'] = A @ U ----
    {
        bf16x8 a0 = *(const bf16x8*)&Alds[wv * 16 + lr][kg * 8];
        bf16x8 a1 = *(const bf16x8*)&Alds[wv * 16 + lr][32 + kg * 8];
        #pragma unroll
        for (int nt = 0; nt < 16; ++nt) {
            int cp = nt * 16 + lr;
            bf16x8 b0 = *(const bf16x8*)&Ulds[cp][kg * 8];
            bf16x8 b1 = *(const bf16x8*)&Ulds[cp][32 + kg * 8];
            f32x4 acc = {0.f, 0.f, 0.f, 0.f};
            acc = MFMA(a0, b0, acc);
            acc = MFMA(a1, b1, acc);
            int vr = (cp >> 6) * 65 + (cp & 63) + 1;      // V[c] at row +1
            bf16x4 pv = {(__bf16)acc[0], (__bf16)acc[1],
                         (__bf16)acc[2], (__bf16)acc[3]};
            *(bf16x4*)&VS[vr][wv * 16 + kg * 4] = pv;
        }
    }
    __syncthreads();

    // ---- Phase 2: chunk scan (waves 0-3, wave = b, lane = mode) ----
    if (wv < 4) {
        int base = wv * 65;
        float sR = 0.f, sI = 0.f;
        float vR = (float)VS[base + 1][ln];
        float vI = (float)VS[base + 1][64 + ln];
        #pragma unroll 2
        for (int c = 0; c < NCH; ++c) {
            VS[base + c][ln]      = (__bf16)sR;     // S[c] (state pre-chunk c)
            VS[base + c][64 + ln] = (__bf16)(-sI);  // store -Im for the matmul
            float nvR = 0.f, nvI = 0.f;
            if (c < NCH - 1) {
                nvR = (float)VS[base + c + 2][ln];
                nvI = (float)VS[base + c + 2][64 + ln];
            }
            float nR = fmaf(aR, sR, fmaf(-aI, sI, vR));
            float nI = fmaf(aR, sI, fmaf(aI, sR, vI));
            sR = nR; sI = nI; vR = nvR; vI = nvI;
        }
    }
    __syncthreads();

    // ---- Phase 3: Y = W @ S + TriK @ U, + D*u, store ----
    {
        int mt  = wv & 3;                 // t-tile
        int nt0 = (wv >> 2) * 8;
        int trow = mt * 16 + lr;
        bf16x8 w0 = *(const bf16x8*)&Wlds[trow][kg * 8];
        bf16x8 w1 = *(const bf16x8*)&Wlds[trow][32 + kg * 8];
        bf16x8 w2 = *(const bf16x8*)&Wlds[trow][64 + kg * 8];
        bf16x8 w3 = *(const bf16x8*)&Wlds[trow][96 + kg * 8];
        bf16x8 k0 = *(const bf16x8*)&Klds[trow][kg * 8];
        bf16x8 k1 = *(const bf16x8*)&Klds[trow][32 + kg * 8];
        #pragma unroll
        for (int nt = nt0; nt < nt0 + 8; ++nt) {
            int cp = nt * 16 + lr;
            int vr = cp + (cp >> 6);      // S row (c' + b)
            f32x4 acc = {0.f, 0.f, 0.f, 0.f};
            acc = MFMA(w0, *(const bf16x8*)&VS[vr][kg * 8],      acc);
            acc = MFMA(w1, *(const bf16x8*)&VS[vr][32 + kg * 8], acc);
            acc = MFMA(w2, *(const bf16x8*)&VS[vr][64 + kg * 8], acc);
            acc = MFMA(w3, *(const bf16x8*)&VS[vr][96 + kg * 8], acc);
            acc = MFMA(k0, *(const bf16x8*)&Ulds[cp][kg * 8],      acc);
            acc = MFMA(k1, *(const bf16x8*)&Ulds[cp][32 + kg * 8], acc);
            int b = cp >> 6, c = cp & 63, t0 = mt * 16 + kg * 4;
            bf16x4 uq = *(const bf16x4*)&Ulds[cp][t0];
            f32x4 res;
            res[0] = fmaf(Dh, (float)uq[0], acc[0]);
            res[1] = fmaf(Dh, (float)uq[1], acc[1]);
            res[2] = fmaf(Dh, (float)uq[2], acc[2]);
            res[3] = fmaf(Dh, (float)uq[3], acc[3]);
            *(f32x4*)&yt[((size_t)(b * H_ + h)) * L_ + c * 64 + t0] = res;
        }
    }
}

// ---------------------------------------------------------------------------
// k_out: out[b,l,h] = yt[b,h,l]  (64x64 LDS tile transpose)
// ---------------------------------------------------------------------------
__global__ __launch_bounds__(256) void k_out(
    const float* __restrict__ yt, float* __restrict__ out)
{
    __shared__ float tile[64][65];
    int h0 = blockIdx.x * 64, l0 = blockIdx.y * 64, b = blockIdx.z;
    int tx = threadIdx.x & 63;
    int ty = threadIdx.x >> 6;
    #pragma unroll
    for (int r = 0; r < 16; ++r) {
        int hy = r * 4 + ty;
        tile[hy][tx] = yt[((size_t)(b * H_ + h0 + hy)) * L_ + l0 + tx];
    }
    __syncthreads();
    #pragma unroll
    for (int r = 0; r < 16; ++r) {
        int ly = r * 4 + ty;
        out[((size_t)b * L_ + (l0 + ly)) * H_ + h0 + tx] = tile[tx][ly];
    }
}

// ---------------------------------------------------------------------------
extern "C" void kernel_launch(void* const* d_in, const int* in_sizes, int n_in,
                              void* d_out, int out_size, void* d_ws, size_t ws_size,
                              hipStream_t stream)
{
    const float* x     = (const float*)d_in[0];
    const float* gamma = (const float*)d_in[1];
    const float* beta  = (const float*)d_in[2];
    const float* LR    = (const float*)d_in[3];
    const float* LI    = (const float*)d_in[4];
    const float* CR    = (const float*)d_in[5];
    const float* CI    = (const float*)d_in[6];
    const float* D     = (const float*)d_in[7];
    float* out = (float*)d_out;

    const size_t BHL = (size_t)B_ * H_ * L_;

    // workspace layout
    float*  xt   = (float*)d_ws;                    // B*H*L (in-place xt->yt)
    float2* st   = (float2*)(xt + BHL);             // B*L
    float*  Crr  = (float*)(st + (size_t)B_ * L_);  // H*N
    float*  Cii  = Crr + (size_t)H_ * N_;
    float*  PR   = Cii + (size_t)H_ * N_;           // 65*64
    float*  PI   = PR + 65 * N_;
    float*  AR64 = PI + 65 * N_;                    // 64
    float*  AI64 = AR64 + N_;
    __bf16* Ag   = (__bf16*)(AI64 + N_);            // 128*64 bf16

    k_prep  <<<dim3((H_ * N_) / 256), dim3(256), 0, stream>>>(LR, LI, CR, CI, Crr, Cii);
    k_tables<<<dim3(65),              dim3(64),  0, stream>>>(LR, LI, PR, PI, AR64, AI64, Ag);
    k_stats <<<dim3(B_ * L_),         dim3(256), 0, stream>>>(x, st);
    k_norm_t<<<dim3(H_/64, L_/64, B_), dim3(256), 0, stream>>>(x, st, gamma, beta, xt);
    k_main  <<<dim3(H_),              dim3(512), 0, stream>>>(xt, xt, Crr, Cii, PR, PI, AR64, AI64, Ag, D);
    k_out   <<<dim3(H_/64, L_/64, B_), dim3(256), 0, stream>>>(xt, out);
}